// Round 1
// baseline (10162.151 us; speedup 1.0000x reference)
//
#include <hip/hip_runtime.h>
#include <math.h>

#define Bn 128
#define Tn 64
#define Cn 64
#define Wn 27
#define Hn 128
#define EPSf 1e-5f
#define NBWf 3456.0f

// normalize coefficients from raw (sum, sumsq) per channel
__device__ __forceinline__ void bn_coef(const float* __restrict__ sums,
                                        const float* __restrict__ g,
                                        const float* __restrict__ b,
                                        int c, float& sc, float& sh) {
  float s1 = sums[2 * c], s2 = sums[2 * c + 1];
  float mean = s1 * (1.0f / NBWf);
  float var = s2 * (1.0f / NBWf) - mean * mean;
  sc = g[c] * rsqrtf(var + EPSf);
  sh = b[c] - mean * sc;
}

// gates = conv1d([x, h], wt) + bias ; reset=sigmoid(o<128) -> rh = reset*h ;
// update=sigmoid(o>=128) -> upd.  x either raw input slice (xpre==null) or
// normalized pre tensor.  h is normalized pre tensor (prev step), or zero.
__global__ __launch_bounds__(256) void k_gates(
    const float* __restrict__ in, int t,
    const float* __restrict__ xpre, const float* __restrict__ xsums,
    const float* __restrict__ xg, const float* __restrict__ xb,
    const float* __restrict__ hpre, const float* __restrict__ hsums,
    const float* __restrict__ hg, const float* __restrict__ hb, int hvalid,
    const float* __restrict__ wt, const float* __restrict__ gbias, int in_c,
    float* __restrict__ rh, float* __restrict__ upd) {
  __shared__ float lds[256 * 29 + 8];
  int b = blockIdx.x;
  int wbase = blockIdx.y * 9;
  int tid = threadIdx.x;
  int rows = in_c + Hn;
  for (int r = tid; r < rows; r += 256) {
    float* dst = &lds[r * 29];
    dst[0] = 0.f;
    dst[28] = 0.f;
    if (r < in_c) {
      if (xpre) {
        float sc, sh;
        bn_coef(xsums, xg, xb, r, sc, sh);
        const float* s = xpre + ((size_t)b * Hn + r) * Wn;
        for (int w = 0; w < Wn; ++w) dst[1 + w] = s[w] * sc + sh;
      } else {
        const float* s = in + (((size_t)b * Tn + t) * Cn + r) * Wn;
        for (int w = 0; w < Wn; ++w) dst[1 + w] = s[w];
      }
    } else {
      int c = r - in_c;
      if (hvalid) {
        float sc, sh;
        bn_coef(hsums, hg, hb, c, sc, sh);
        const float* s = hpre + ((size_t)b * Hn + c) * Wn;
        for (int w = 0; w < Wn; ++w) dst[1 + w] = s[w] * sc + sh;
      } else {
        for (int w = 0; w < Wn; ++w) dst[1 + w] = 0.f;
      }
    }
  }
  __syncthreads();

  int o = tid;  // 256 output channels
  float acc[9];
#pragma unroll
  for (int j = 0; j < 9; ++j) acc[j] = 0.f;
  int tot = hvalid ? rows : in_c;
  for (int i = 0; i < tot; ++i) {
    float w0v = wt[(3 * i + 0) * 256 + o];
    float w1v = wt[(3 * i + 1) * 256 + o];
    float w2v = wt[(3 * i + 2) * 256 + o];
    const float* row = &lds[i * 29 + wbase];
    float xv[11];
#pragma unroll
    for (int j = 0; j < 11; ++j) xv[j] = row[j];
#pragma unroll
    for (int j = 0; j < 9; ++j)
      acc[j] = fmaf(w2v, xv[j + 2], fmaf(w1v, xv[j + 1], fmaf(w0v, xv[j], acc[j])));
  }
  float bias = gbias[o];
  if (o < Hn) {
#pragma unroll
    for (int j = 0; j < 9; ++j) {
      int w = wbase + j;
      float gv = 1.f / (1.f + expf(-(acc[j] + bias)));
      float hn = lds[(in_c + o) * 29 + 1 + w];  // normalized h (0 if !hvalid)
      rh[((size_t)b * Hn + o) * Wn + w] = gv * hn;
    }
  } else {
    int c = o - Hn;
#pragma unroll
    for (int j = 0; j < 9; ++j) {
      int w = wbase + j;
      upd[((size_t)b * Hn + c) * Wn + w] = 1.f / (1.f + expf(-(acc[j] + bias)));
    }
  }
}

// cnm = conv1d([x, rh], wtc)+cb + conv1d(a, wta)+ab ;
// pre = mish((1-u)*h_norm + u*cnm) ; store pre ; accumulate per-channel sums.
__global__ __launch_bounds__(256) void k_cnm(
    const float* __restrict__ in, int t,
    const float* __restrict__ xpre, const float* __restrict__ xsums,
    const float* __restrict__ xg, const float* __restrict__ xb,
    const float* __restrict__ rh, const float* __restrict__ upd,
    const float* __restrict__ hpre, const float* __restrict__ hsums,
    const float* __restrict__ hg, const float* __restrict__ hb, int hvalid,
    const float* __restrict__ wtc, const float* __restrict__ cbias,
    const float* __restrict__ wta, const float* __restrict__ abias, int in_c,
    float* __restrict__ pre_out, float* __restrict__ sums_out) {
  __shared__ float lds[264 * 29 + 8];
  int b = blockIdx.x;
  int tid = threadIdx.x;
  int rows = in_c + Hn + 8;
  for (int r = tid; r < rows; r += 256) {
    float* dst = &lds[r * 29];
    dst[0] = 0.f;
    dst[28] = 0.f;
    if (r < in_c) {
      if (xpre) {
        float sc, sh;
        bn_coef(xsums, xg, xb, r, sc, sh);
        const float* s = xpre + ((size_t)b * Hn + r) * Wn;
        for (int w = 0; w < Wn; ++w) dst[1 + w] = s[w] * sc + sh;
      } else {
        const float* s = in + (((size_t)b * Tn + t) * Cn + r) * Wn;
        for (int w = 0; w < Wn; ++w) dst[1 + w] = s[w];
      }
    } else if (r < in_c + Hn) {
      int c = r - in_c;
      const float* s = rh + ((size_t)b * Hn + c) * Wn;
      for (int w = 0; w < Wn; ++w) dst[1 + w] = s[w];
    } else {
      int c = r - in_c - Hn;  // 0..7 -> input channels 56..63
      const float* s = in + (((size_t)b * Tn + t) * Cn + 56 + c) * Wn;
      for (int w = 0; w < Wn; ++w) dst[1 + w] = s[w];
    }
  }
  __syncthreads();

  int o = tid & 127;
  int half = tid >> 7;
  int wbase = blockIdx.y * 9 + half * 5;
  int nw = half ? 4 : 5;
  float acc[5];
#pragma unroll
  for (int j = 0; j < 5; ++j) acc[j] = 0.f;

  for (int i = 0; i < in_c; ++i) {  // x part
    float w0v = wtc[(3 * i + 0) * 128 + o];
    float w1v = wtc[(3 * i + 1) * 128 + o];
    float w2v = wtc[(3 * i + 2) * 128 + o];
    const float* row = &lds[i * 29 + wbase];
    float xv[7];
#pragma unroll
    for (int j = 0; j < 7; ++j) xv[j] = row[j];
#pragma unroll
    for (int j = 0; j < 5; ++j)
      acc[j] = fmaf(w2v, xv[j + 2], fmaf(w1v, xv[j + 1], fmaf(w0v, xv[j], acc[j])));
  }
  if (hvalid) {
    for (int i = 0; i < Hn; ++i) {  // reset*h part
      int ii = in_c + i;
      float w0v = wtc[(3 * ii + 0) * 128 + o];
      float w1v = wtc[(3 * ii + 1) * 128 + o];
      float w2v = wtc[(3 * ii + 2) * 128 + o];
      const float* row = &lds[ii * 29 + wbase];
      float xv[7];
#pragma unroll
      for (int j = 0; j < 7; ++j) xv[j] = row[j];
#pragma unroll
      for (int j = 0; j < 5; ++j)
        acc[j] = fmaf(w2v, xv[j + 2], fmaf(w1v, xv[j + 1], fmaf(w0v, xv[j], acc[j])));
    }
  }
  for (int i = 0; i < 8; ++i) {  // cond part
    float w0v = wta[(3 * i + 0) * 128 + o];
    float w1v = wta[(3 * i + 1) * 128 + o];
    float w2v = wta[(3 * i + 2) * 128 + o];
    const float* row = &lds[(in_c + Hn + i) * 29 + wbase];
    float xv[7];
#pragma unroll
    for (int j = 0; j < 7; ++j) xv[j] = row[j];
#pragma unroll
    for (int j = 0; j < 5; ++j)
      acc[j] = fmaf(w2v, xv[j + 2], fmaf(w1v, xv[j + 1], fmaf(w0v, xv[j], acc[j])));
  }

  float cb0v = cbias[o] + abias[o];
  float hsc = 0.f, hsh = 0.f;
  if (hvalid) bn_coef(hsums, hg, hb, o, hsc, hsh);
  float s1 = 0.f, s2 = 0.f;
  for (int j = 0; j < nw; ++j) {
    int w = wbase + j;
    size_t offe = ((size_t)b * Hn + o) * Wn + w;
    float u = upd[offe];
    float hn = hvalid ? (hpre[offe] * hsc + hsh) : 0.f;
    float z = (1.f - u) * hn + u * (acc[j] + cb0v);
    float sp = (z > 20.f) ? z : log1pf(expf(z));
    float pv = z * tanhf(sp);
    pre_out[offe] = pv;
    s1 += pv;
    s2 += pv * pv;
  }
  __shared__ float rs[256], rq[256];
  rs[tid] = s1;
  rq[tid] = s2;
  __syncthreads();
  if (tid < 128) {
    atomicAdd(&sums_out[2 * tid], rs[tid] + rs[tid + 128]);
    atomicAdd(&sums_out[2 * tid + 1], rq[tid] + rq[tid + 128]);
  }
}

__global__ __launch_bounds__(256) void k_out(
    const float* __restrict__ p63, const float* __restrict__ s63,
    const float* __restrict__ p62, const float* __restrict__ s62,
    const float* __restrict__ g, const float* __restrict__ bb,
    const float* __restrict__ concw, float* __restrict__ out) {
  int b = blockIdx.x, tid = threadIdx.x;
  float acc = 0.f;
  for (int idx = tid; idx < Hn * Wn; idx += 256) {
    int o = idx / Wn;
    float sc3, sh3, sc2, sh2;
    bn_coef(s63, g, bb, o, sc3, sh3);
    bn_coef(s62, g, bb, o, sc2, sh2);
    float v3 = p63[(size_t)b * Hn * Wn + idx] * sc3 + sh3;
    float v2 = p62[(size_t)b * Hn * Wn + idx] * sc2 + sh2;
    acc += (v3 - v2) * concw[idx];
  }
  __shared__ float red[256];
  red[tid] = acc;
  __syncthreads();
  for (int s = 128; s > 0; s >>= 1) {
    if (tid < s) red[tid] += red[tid + s];
    __syncthreads();
  }
  if (tid == 0) out[b] = 0.99f * red[0];
}

// transpose (M, IC, 3) -> [(i*3+k)][o] for coalesced weight loads
__global__ void k_twt(const float* __restrict__ src, float* __restrict__ dst,
                      int M, int IC) {
  int idx = blockIdx.x * 256 + threadIdx.x;
  int total = M * IC * 3;
  if (idx >= total) return;
  int o = idx % M;
  int rem = idx / M;  // i*3+k
  int i = rem / 3, k = rem - 3 * i;
  dst[idx] = src[((size_t)o * IC + i) * 3 + k];
}

extern "C" void kernel_launch(void* const* d_in, const int* in_sizes, int n_in,
                              void* d_out, int out_size, void* d_ws,
                              size_t ws_size, hipStream_t stream) {
  const float* in = (const float*)d_in[0];
  const float* gw0 = (const float*)d_in[1];
  const float* gb0 = (const float*)d_in[2];
  const float* cw0 = (const float*)d_in[3];
  const float* cb0 = (const float*)d_in[4];
  const float* aw0 = (const float*)d_in[5];
  const float* ab0 = (const float*)d_in[6];
  const float* bg0 = (const float*)d_in[7];
  const float* bb0 = (const float*)d_in[8];
  const float* gw1 = (const float*)d_in[9];
  const float* gb1 = (const float*)d_in[10];
  const float* cw1 = (const float*)d_in[11];
  const float* cb1 = (const float*)d_in[12];
  const float* aw1 = (const float*)d_in[13];
  const float* ab1 = (const float*)d_in[14];
  const float* bg1 = (const float*)d_in[15];
  const float* bb1 = (const float*)d_in[16];
  const float* concw = (const float*)d_in[17];
  float* out = (float*)d_out;

  float* ws = (float*)d_ws;
  size_t off = 0;
  float* wt_g0 = ws + off; off += 576 * 256;
  float* wt_c0 = ws + off; off += 576 * 128;
  float* wt_a0 = ws + off; off += 24 * 128;
  float* wt_g1 = ws + off; off += 768 * 256;
  float* wt_c1 = ws + off; off += 768 * 128;
  float* wt_a1 = ws + off; off += 24 * 128;
  const size_t PRE = (size_t)Bn * Hn * Wn;  // 442368
  float* pre1[2] = {ws + off, ws + off + PRE}; off += 2 * PRE;
  float* pre2[2] = {ws + off, ws + off + PRE}; off += 2 * PRE;
  float* rh = ws + off; off += PRE;
  float* upd = ws + off; off += PRE;
  float* sums = ws + off; off += 2 * 64 * 128 * 2;
  if (ws_size < off * sizeof(float)) return;  // insufficient scratch: fail loudly

  hipMemsetAsync(sums, 0, 2 * 64 * 128 * 2 * sizeof(float), stream);

  auto tw = [&](const float* s, float* d, int M, int IC) {
    int tot = M * IC * 3;
    k_twt<<<(tot + 255) / 256, 256, 0, stream>>>(s, d, M, IC);
  };
  tw(gw0, wt_g0, 256, 192);
  tw(cw0, wt_c0, 128, 192);
  tw(aw0, wt_a0, 128, 8);
  tw(gw1, wt_g1, 256, 256);
  tw(cw1, wt_c1, 128, 256);
  tw(aw1, wt_a1, 128, 8);

  auto sl = [&](int layer, int t) {
    return sums + ((size_t)(layer * 64 + t) * 128) * 2;
  };

  for (int t = 0; t < 64; ++t) {
    int hv = (t > 0) ? 1 : 0;
    const float* s0p = sl(0, hv ? t - 1 : 0);
    const float* s1p = sl(1, hv ? t - 1 : 0);
    // layer 0
    k_gates<<<dim3(Bn, 3), 256, 0, stream>>>(
        in, t, nullptr, nullptr, nullptr, nullptr,
        pre1[(t + 1) & 1], s0p, bg0, bb0, hv,
        wt_g0, gb0, Cn, rh, upd);
    k_cnm<<<dim3(Bn, 3), 256, 0, stream>>>(
        in, t, nullptr, nullptr, nullptr, nullptr,
        rh, upd,
        pre1[(t + 1) & 1], s0p, bg0, bb0, hv,
        wt_c0, cb0, wt_a0, ab0, Cn,
        pre1[t & 1], sl(0, t));
    // layer 1 (x = normalized h1[t])
    k_gates<<<dim3(Bn, 3), 256, 0, stream>>>(
        in, t, pre1[t & 1], sl(0, t), bg0, bb0,
        pre2[(t + 1) & 1], s1p, bg1, bb1, hv,
        wt_g1, gb1, Hn, rh, upd);
    k_cnm<<<dim3(Bn, 3), 256, 0, stream>>>(
        in, t, pre1[t & 1], sl(0, t), bg0, bb0,
        rh, upd,
        pre2[(t + 1) & 1], s1p, bg1, bb1, hv,
        wt_c1, cb1, wt_a1, ab1, Hn,
        pre2[t & 1], sl(1, t));
  }
  // t=63 -> pre2[1], t=62 -> pre2[0]
  k_out<<<Bn, 256, 0, stream>>>(pre2[1], sl(1, 63), pre2[0], sl(1, 62),
                                bg1, bb1, concw, out);
}

// Round 2
// 6795.219 us; speedup vs baseline: 1.4955x; 1.4955x over previous
//
#include <hip/hip_runtime.h>
#include <math.h>

#define Bn 128
#define Tn 64
#define Cn 64
#define Wn 27
#define Hn 128
#define EPSf 1e-5f
#define NBWf 3456.0f

__device__ __forceinline__ void bn_coef(const float* __restrict__ sums,
                                        const float* __restrict__ g,
                                        const float* __restrict__ b,
                                        int c, float& sc, float& sh) {
  float s1 = sums[2 * c], s2 = sums[2 * c + 1];
  float mean = s1 * (1.0f / NBWf);
  float var = s2 * (1.0f / NBWf) - mean * mean;
  sc = g[c] * rsqrtf(var + EPSf);
  sh = b[c] - mean * sc;
}

__device__ __forceinline__ float sigm(float x) {
  return 1.0f / (1.0f + __expf(-x));
}

// Fused per-(layer,t) step kernel. Block = (batch b, w-half y).
// y=0: staged w in [-1..15] (c=0..16), gate positions c=1..15 (w 0..14),
//      cnm outputs c=1..14 (w 0..13).
// y=1: staged w in [12..27] (c=0..15), gate positions c=1..14 (w 13..26),
//      cnm outputs c=2..14 (w 14..26).
// rh/upd live in LDS; BN partial sums -> atomics.
template <int IC, bool XN, bool HV>
__global__ __launch_bounds__(512, 1) void k_step(
    const float* __restrict__ in, int t,
    const float* __restrict__ xpre, const float* __restrict__ xsums,
    const float* __restrict__ xg, const float* __restrict__ xb,
    const float* __restrict__ hpre, const float* __restrict__ hsums,
    const float* __restrict__ hg, const float* __restrict__ hb,
    const float* __restrict__ wtg, const float* __restrict__ gbias,
    const float* __restrict__ wtc, const float* __restrict__ cbias,
    const float* __restrict__ wta, const float* __restrict__ abias,
    float* __restrict__ pre_out, float* __restrict__ sums_out) {
  constexpr int ROWS = IC + 136;  // IC x-rows, 128 h-rows, 8 cond rows
  __shared__ float lx[ROWS * 17 + 8];
  __shared__ float lrh[128 * 17 + 8];
  __shared__ float lu[128 * 17 + 8];
  __shared__ float red1[512];
  __shared__ float red2[512];
  const int b = blockIdx.x;
  const int y = blockIdx.y;
  const int wlo = y ? 12 : -1;
  const int tid = threadIdx.x;

  // ---- stage normalized x rows, normalized h rows, cond rows ----
  for (int r = tid; r < ROWS; r += 512) {
    float sc = 1.f, sh = 0.f;
    const float* src = nullptr;
    if (r < IC) {
      if (XN) {
        bn_coef(xsums, xg, xb, r, sc, sh);
        src = xpre + ((size_t)b * Hn + r) * Wn;
      } else {
        src = in + (((size_t)b * Tn + t) * Cn + r) * Wn;
      }
    } else if (r < IC + 128) {
      if (HV) {
        bn_coef(hsums, hg, hb, r - IC, sc, sh);
        src = hpre + ((size_t)b * Hn + (r - IC)) * Wn;
      }
    } else {
      src = in + (((size_t)b * Tn + t) * Cn + 56 + (r - IC - 128)) * Wn;
    }
    float* dst = &lx[r * 17];
#pragma unroll
    for (int c = 0; c < 17; ++c) {
      int w = wlo + c;
      float v = 0.f;
      if (src && (unsigned)w < 27u) v = src[w] * sc + sh;
      dst[c] = v;
    }
  }
  __syncthreads();

  // ---- gates: 256 channels x 2 w-segments ----
  {
    const int GP = y ? 14 : 15;
    const int och = tid & 255;
    const int seg = tid >> 8;
    const int c0 = 1 + seg * 8;
    float acc[8] = {0, 0, 0, 0, 0, 0, 0, 0};
    const float* wp = wtg + och;
    const int rows = HV ? IC + 128 : IC;
#pragma unroll 2
    for (int i = 0; i < rows; ++i) {
      float w0 = wp[0], w1 = wp[256], w2 = wp[512];
      wp += 768;
      const float* row = &lx[i * 17 + c0 - 1];
      float xv[10];
#pragma unroll
      for (int j = 0; j < 10; ++j) xv[j] = row[j];
#pragma unroll
      for (int j = 0; j < 8; ++j)
        acc[j] = fmaf(w2, xv[j + 2], fmaf(w1, xv[j + 1], fmaf(w0, xv[j], acc[j])));
    }
    float bias = gbias[och];
    if (och < 128) {
#pragma unroll
      for (int j = 0; j < 8; ++j) {
        int c = c0 + j;
        float g = sigm(acc[j] + bias);
        float hn = lx[(IC + och) * 17 + c];
        lrh[och * 17 + c] = (c <= GP) ? g * hn : 0.f;
      }
      if (seg == 0) lrh[och * 17] = 0.f;  // w-padding column
    } else {
      const int ch = och - 128;
#pragma unroll
      for (int j = 0; j < 8; ++j) {
        int c = c0 + j;
        if (c <= GP) lu[ch * 17 + c] = sigm(acc[j] + bias);
      }
    }
  }
  __syncthreads();

  // ---- cnm conv + mish + BN partial sums: 128 channels x 4 w-segments ----
  {
    const int ch = tid & 127;
    const int seg = tid >> 7;
    const int c0 = (y ? 2 : 1) + seg * 4;
    float acc[4] = {0, 0, 0, 0};
    const float* wp = wtc + ch;
#pragma unroll 2
    for (int i = 0; i < IC; ++i) {
      float w0 = wp[0], w1 = wp[128], w2 = wp[256];
      wp += 384;
      const float* row = &lx[i * 17 + c0 - 1];
      float xv[6];
#pragma unroll
      for (int j = 0; j < 6; ++j) xv[j] = row[j];
#pragma unroll
      for (int j = 0; j < 4; ++j)
        acc[j] = fmaf(w2, xv[j + 2], fmaf(w1, xv[j + 1], fmaf(w0, xv[j], acc[j])));
    }
    if (HV) {
#pragma unroll 2
      for (int i = 0; i < 128; ++i) {
        float w0 = wp[0], w1 = wp[128], w2 = wp[256];
        wp += 384;
        const float* row = &lrh[i * 17 + c0 - 1];
        float xv[6];
#pragma unroll
        for (int j = 0; j < 6; ++j) xv[j] = row[j];
#pragma unroll
        for (int j = 0; j < 4; ++j)
          acc[j] = fmaf(w2, xv[j + 2], fmaf(w1, xv[j + 1], fmaf(w0, xv[j], acc[j])));
      }
    }
    {
      const float* wap = wta + ch;
#pragma unroll
      for (int i = 0; i < 8; ++i) {
        float w0 = wap[0], w1 = wap[128], w2 = wap[256];
        wap += 384;
        const float* row = &lx[(IC + 128 + i) * 17 + c0 - 1];
        float xv[6];
#pragma unroll
        for (int j = 0; j < 6; ++j) xv[j] = row[j];
#pragma unroll
        for (int j = 0; j < 4; ++j)
          acc[j] = fmaf(w2, xv[j + 2], fmaf(w1, xv[j + 1], fmaf(w0, xv[j], acc[j])));
      }
    }
    const float cb = cbias[ch] + abias[ch];
    float s1 = 0.f, s2 = 0.f;
#pragma unroll
    for (int j = 0; j < 4; ++j) {
      int c = c0 + j;
      if (c <= 14) {
        float u = lu[ch * 17 + c];
        float hn = lx[(IC + ch) * 17 + c];  // already-normalized h (0 if !HV)
        float z = (1.f - u) * hn + u * (acc[j] + cb);
        float pv;
        if (z > 20.f) {
          pv = z;
        } else {
          float q = 1.f + __expf(z);
          float q2 = q * q;
          pv = z * (q2 - 1.f) / (q2 + 1.f);  // z*tanh(softplus(z))
        }
        pre_out[((size_t)b * Hn + ch) * Wn + (wlo + c)] = pv;
        s1 += pv;
        s2 += pv * pv;
      }
    }
    red1[tid] = s1;
    red2[tid] = s2;
  }
  __syncthreads();
  if (tid < 128) {
    float a1 = red1[tid] + red1[tid + 128] + red1[tid + 256] + red1[tid + 384];
    float a2 = red2[tid] + red2[tid + 128] + red2[tid + 256] + red2[tid + 384];
    atomicAdd(&sums_out[2 * tid], a1);
    atomicAdd(&sums_out[2 * tid + 1], a2);
  }
}

__global__ __launch_bounds__(256) void k_out(
    const float* __restrict__ p63, const float* __restrict__ s63,
    const float* __restrict__ p62, const float* __restrict__ s62,
    const float* __restrict__ g, const float* __restrict__ bb,
    const float* __restrict__ concw, float* __restrict__ out) {
  int b = blockIdx.x, tid = threadIdx.x;
  float acc = 0.f;
  for (int idx = tid; idx < Hn * Wn; idx += 256) {
    int o = idx / Wn;
    float sc3, sh3, sc2, sh2;
    bn_coef(s63, g, bb, o, sc3, sh3);
    bn_coef(s62, g, bb, o, sc2, sh2);
    float v3 = p63[(size_t)b * Hn * Wn + idx] * sc3 + sh3;
    float v2 = p62[(size_t)b * Hn * Wn + idx] * sc2 + sh2;
    acc += (v3 - v2) * concw[idx];
  }
  __shared__ float red[256];
  red[tid] = acc;
  __syncthreads();
  for (int s = 128; s > 0; s >>= 1) {
    if (tid < s) red[tid] += red[tid + s];
    __syncthreads();
  }
  if (tid == 0) out[b] = 0.99f * red[0];
}

// transpose (M, IC, 3) -> [(i*3+k)][o]
__global__ void k_twt(const float* __restrict__ src, float* __restrict__ dst,
                      int M, int IC) {
  int idx = blockIdx.x * 256 + threadIdx.x;
  int total = M * IC * 3;
  if (idx >= total) return;
  int o = idx % M;
  int rem = idx / M;  // i*3+k
  int i = rem / 3, k = rem - 3 * i;
  dst[idx] = src[((size_t)o * IC + i) * 3 + k];
}

extern "C" void kernel_launch(void* const* d_in, const int* in_sizes, int n_in,
                              void* d_out, int out_size, void* d_ws,
                              size_t ws_size, hipStream_t stream) {
  const float* in = (const float*)d_in[0];
  const float* gw0 = (const float*)d_in[1];
  const float* gb0 = (const float*)d_in[2];
  const float* cw0 = (const float*)d_in[3];
  const float* cb0 = (const float*)d_in[4];
  const float* aw0 = (const float*)d_in[5];
  const float* ab0 = (const float*)d_in[6];
  const float* bg0 = (const float*)d_in[7];
  const float* bb0 = (const float*)d_in[8];
  const float* gw1 = (const float*)d_in[9];
  const float* gb1 = (const float*)d_in[10];
  const float* cw1 = (const float*)d_in[11];
  const float* cb1 = (const float*)d_in[12];
  const float* aw1 = (const float*)d_in[13];
  const float* ab1 = (const float*)d_in[14];
  const float* bg1 = (const float*)d_in[15];
  const float* bb1 = (const float*)d_in[16];
  const float* concw = (const float*)d_in[17];
  float* out = (float*)d_out;

  float* ws = (float*)d_ws;
  size_t off = 0;
  float* wt_g0 = ws + off; off += 576 * 256;
  float* wt_c0 = ws + off; off += 576 * 128;
  float* wt_a0 = ws + off; off += 24 * 128;
  float* wt_g1 = ws + off; off += 768 * 256;
  float* wt_c1 = ws + off; off += 768 * 128;
  float* wt_a1 = ws + off; off += 24 * 128;
  const size_t PRE = (size_t)Bn * Hn * Wn;  // 442368
  float* pre1[2] = {ws + off, ws + off + PRE}; off += 2 * PRE;
  float* pre2[2] = {ws + off, ws + off + PRE}; off += 2 * PRE;
  float* sums = ws + off; off += 2 * 64 * 128 * 2;
  if (ws_size < off * sizeof(float)) return;

  hipMemsetAsync(sums, 0, 2 * 64 * 128 * 2 * sizeof(float), stream);

  auto tw = [&](const float* s, float* d, int M, int IC) {
    int tot = M * IC * 3;
    k_twt<<<(tot + 255) / 256, 256, 0, stream>>>(s, d, M, IC);
  };
  tw(gw0, wt_g0, 256, 192);
  tw(cw0, wt_c0, 128, 192);
  tw(aw0, wt_a0, 128, 8);
  tw(gw1, wt_g1, 256, 256);
  tw(cw1, wt_c1, 128, 256);
  tw(aw1, wt_a1, 128, 8);

  auto sl = [&](int layer, int t) {
    return sums + ((size_t)(layer * 64 + t) * 128) * 2;
  };

  dim3 grd(Bn, 2);
  for (int t = 0; t < 64; ++t) {
    if (t == 0) {
      k_step<64, false, false><<<grd, 512, 0, stream>>>(
          in, t, nullptr, nullptr, nullptr, nullptr,
          nullptr, nullptr, nullptr, nullptr,
          wt_g0, gb0, wt_c0, cb0, wt_a0, ab0, pre1[0], sl(0, 0));
      k_step<128, true, false><<<grd, 512, 0, stream>>>(
          in, t, pre1[0], sl(0, 0), bg0, bb0,
          nullptr, nullptr, nullptr, nullptr,
          wt_g1, gb1, wt_c1, cb1, wt_a1, ab1, pre2[0], sl(1, 0));
    } else {
      k_step<64, false, true><<<grd, 512, 0, stream>>>(
          in, t, nullptr, nullptr, nullptr, nullptr,
          pre1[(t + 1) & 1], sl(0, t - 1), bg0, bb0,
          wt_g0, gb0, wt_c0, cb0, wt_a0, ab0, pre1[t & 1], sl(0, t));
      k_step<128, true, true><<<grd, 512, 0, stream>>>(
          in, t, pre1[t & 1], sl(0, t), bg0, bb0,
          pre2[(t + 1) & 1], sl(1, t - 1), bg1, bb1,
          wt_g1, gb1, wt_c1, cb1, wt_a1, ab1, pre2[t & 1], sl(1, t));
    }
  }
  k_out<<<Bn, 256, 0, stream>>>(pre2[1], sl(1, 63), pre2[0], sl(1, 62),
                                bg1, bb1, concw, out);
}